// Round 5
// baseline (592.116 us; speedup 1.0000x reference)
//
#include <hip/hip_runtime.h>
#include <hip/hip_bf16.h>

typedef __bf16 bf16_t;
typedef __attribute__((ext_vector_type(8))) __bf16 bf16x8;
typedef __attribute__((ext_vector_type(4))) float f32x4;
typedef __attribute__((ext_vector_type(8))) unsigned short ushort8v;

#define MFMA16(a, b, c) __builtin_amdgcn_mfma_f32_16x16x32_bf16((a), (b), (c), 0, 0, 0)
#define BC8(x) __builtin_bit_cast(bf16x8, (x))

__device__ __forceinline__ unsigned short f2bf(float f) {
    bf16_t b = (bf16_t)f;
    return __builtin_bit_cast(unsigned short, b);
}

__device__ __forceinline__ void gload16(const void* g, void* l) {
    __builtin_amdgcn_global_load_lds(
        (const __attribute__((address_space(1))) void*)g,
        (__attribute__((address_space(3))) void*)l,
        16, 0, 0);
}

// ---------- fp32 -> bf16 elementwise convert (for X) ----------
__global__ __launch_bounds__(256) void cvtx(const float* __restrict__ src,
                                            bf16_t* __restrict__ dst) {
    size_t i = ((size_t)blockIdx.x * 256 + threadIdx.x) * 8;
    f32x4 v0 = *(const f32x4*)(src + i);
    f32x4 v1 = *(const f32x4*)(src + i + 4);
    bf16x8 o;
    o[0] = (bf16_t)v0[0]; o[1] = (bf16_t)v0[1];
    o[2] = (bf16_t)v0[2]; o[3] = (bf16_t)v0[3];
    o[4] = (bf16_t)v1[0]; o[5] = (bf16_t)v1[1];
    o[6] = (bf16_t)v1[2]; o[7] = (bf16_t)v1[3];
    *(bf16x8*)(dst + i) = o;
}

// ---------- batched 64x64 transpose + fp32->bf16 convert ----------
__global__ __launch_bounds__(256) void transcvt64(const float* __restrict__ src,
                                                  unsigned short* __restrict__ dst,
                                                  int R, int C) {
    __shared__ __align__(16) unsigned short tile[64][66];
    size_t off = (size_t)blockIdx.z * R * C;
    const float* s = src + off;
    unsigned short* d = dst + off;
    int tr = blockIdx.y * 64, tc = blockIdx.x * 64;
    int tid = threadIdx.x;
    int lr = tid >> 4;
    int lc = (tid & 15) * 4;
#pragma unroll
    for (int p = 0; p < 4; ++p) {
        int r = p * 16 + lr;
        f32x4 v = *(const f32x4*)(s + (size_t)(tr + r) * C + tc + lc);
        tile[r][lc + 0] = f2bf(v[0]); tile[r][lc + 1] = f2bf(v[1]);
        tile[r][lc + 2] = f2bf(v[2]); tile[r][lc + 3] = f2bf(v[3]);
    }
    __syncthreads();
#pragma unroll
    for (int q = 0; q < 2; ++q) {
        int item = q * 256 + tid;
        int oc = item >> 3;            // column 0..63
        int rb = (item & 7) * 8;       // row octet
        ushort8v v;
#pragma unroll
        for (int t = 0; t < 8; ++t) v[t] = tile[rb + t][oc];
        *(ushort8v*)(d + (size_t)(tc + oc) * R + tr + rb) = v;
    }
}

// =====================================================================
// Ring-buffered GEMMs with REGISTER-LEVEL fragment double-buffer.
// Per half h: lgkmcnt(0) [drains reads issued one half ago, ~free] ->
// issue 12 ds_read_b128 for half h+1 into the other reg bank ->
// sched_barrier(0) -> 32 MFMA on this half's bank -> counted vmcnt ->
// s_barrier. LDS reads service UNDER the MFMA cluster (the measured
// ~1600 cyc/half serialization in R1/R2/R4).
// Max DS outstanding = 12 (lgkmcnt is 4-bit). Max VMEM outstanding = 12.
// Safety ledger (per half h):
//   reads(h+1) target slot (h+1)&3; staged-complete: VMW(4) at end of
//     half h-1 forces stage(h+1); barrier makes it cross-wave visible.
//   STG(h+3) at half h writes slot (h-1)&3; its last readers (reads for
//     half h-1, issued at h-2) are drained by every wave's lgkmcnt(0)
//     at top of half h-1; end-of-(h-1) barrier precedes any STG at h.
//   In-flight reads (slot (h+1)&3) never alias any STG target.
// =====================================================================

#define LGKMN(n) { asm volatile("s_waitcnt lgkmcnt(" #n ")" ::: "memory"); \
                   __builtin_amdgcn_sched_barrier(0); }
#define VMW(n) asm volatile("s_waitcnt vmcnt(" #n ")" ::: "memory")
#define DSR(dst, a, OFF) asm volatile("ds_read_b128 %0, %1 " OFF : "=v"(dst) : "v"(a))

// ---------- GEMM1 fused: Hh = silu(X*W1) * (X*W3) ----------
// Tile 256(M) x 128(N), 8 waves = 4M x 2N, per-wave 64x64 dual (U,V).
// Slot bytes: A rows0-127 [0,8192), A rows128-255 [8192,16384),
// B1 [16384,24576), B3 [24576,32768). Slot stride 32768 B.
__global__ __launch_bounds__(512, 2) void gemm13(const bf16_t* __restrict__ Xb,
                                                 const bf16_t* __restrict__ W1t,
                                                 const bf16_t* __restrict__ W3t,
                                                 bf16_t* __restrict__ Hh,
                                                 int row_base) {
    const int K = 1024, N = 2048;
    int nwg = gridDim.x, id = blockIdx.x;
    if ((nwg & 7) == 0) id = (id & 7) * (nwg >> 3) + (id >> 3);  // XCD swizzle
    int nbx = nwg >> 4;
    int bx = id % nbx, by = id / nbx;      // col-major: co-resident share W-panels
    int row0 = bx * 256, col0 = by * 128;
    int seg = ((row_base + row0) & 2047) >> 9;
    const bf16_t* Ag  = Xb + (size_t)row0 * K;
    const bf16_t* B1g = W1t + ((size_t)seg * N + col0) * K;
    const bf16_t* B3g = W3t + ((size_t)seg * N + col0) * K;

    __shared__ __align__(16) bf16_t smem[65536];     // 4 x 32KB slots

    int tid = threadIdx.x, lane = tid & 63, w = tid >> 6;
    int wm = w >> 1, wn = w & 1;
    int quad = lane >> 4, l16 = lane & 15;

    int r0 = 2 * (tid >> 3) + ((tid >> 2) & 1);
    int c0 = (tid & 3) ^ ((tid >> 3) & 3);
    int offG  = r0 * K + c0 * 8;
    int offG2 = offG + 128 * K;

    int sigRd = ((l16 & 1) << 2) | (quad ^ ((l16 >> 1) & 3));
    int rdAB = ((wm * 32 + (l16 >> 1)) * 64 + sigRd * 8) * 2;   // byte addr, A region
    int rdBB = ((wn * 32 + (l16 >> 1)) * 64 + sigRd * 8) * 2;   // byte addr, B region

    f32x4 accU[4][4], accV[4][4];
    f32x4 z = {0.f, 0.f, 0.f, 0.f};
#pragma unroll
    for (int i = 0; i < 4; ++i)
#pragma unroll
        for (int j = 0; j < 4; ++j) { accU[i][j] = z; accV[i][j] = z; }

    f32x4 af[2][4], bU[2][4], bV[2][4];      // two register banks

#define STG13(slot, hh) { bf16_t* d_ = smem + (slot) * 16384; const int kg_ = (hh) * 32; \
    gload16(Ag + kg_ + offG,  d_ + tid * 8); \
    gload16(Ag + kg_ + offG2, d_ + 4096 + tid * 8); \
    gload16(B1g + kg_ + offG, d_ + 8192 + tid * 8); \
    gload16(B3g + kg_ + offG, d_ + 12288 + tid * 8); }

#define RD13(slotN, BN) {                                                       \
    int aA_ = (slotN) * 32768 + rdAB;                                           \
    int aB_ = (slotN) * 32768 + rdBB;                                           \
    DSR(af[BN][0], aA_, "offset:0");     DSR(af[BN][1], aA_, "offset:1024");    \
    DSR(af[BN][2], aA_, "offset:2048");  DSR(af[BN][3], aA_, "offset:3072");    \
    DSR(bU[BN][0], aB_, "offset:16384"); DSR(bU[BN][1], aB_, "offset:17408");   \
    DSR(bU[BN][2], aB_, "offset:18432"); DSR(bU[BN][3], aB_, "offset:19456");   \
    DSR(bV[BN][0], aB_, "offset:24576"); DSR(bV[BN][1], aB_, "offset:25600");   \
    DSR(bV[BN][2], aB_, "offset:26624"); DSR(bV[BN][3], aB_, "offset:27648"); }

#define HALF13(BC, RD, STG, WAIT) {                                             \
    LGKMN(0);                                                                   \
    RD;                                                                         \
    STG;                                                                        \
    __builtin_amdgcn_sched_barrier(0);                                          \
    __builtin_amdgcn_s_setprio(1);                                              \
    _Pragma("unroll")                                                           \
    for (int i_ = 0; i_ < 4; ++i_)                                              \
        _Pragma("unroll")                                                       \
        for (int j_ = 0; j_ < 4; ++j_)                                          \
            accU[i_][j_] = MFMA16(BC8(af[BC][i_]), BC8(bU[BC][j_]), accU[i_][j_]); \
    _Pragma("unroll")                                                           \
    for (int i_ = 0; i_ < 4; ++i_)                                              \
        _Pragma("unroll")                                                       \
        for (int j_ = 0; j_ < 4; ++j_)                                          \
            accV[i_][j_] = MFMA16(BC8(af[BC][i_]), BC8(bV[BC][j_]), accV[i_][j_]); \
    __builtin_amdgcn_s_setprio(0);                                              \
    WAIT;                                                                       \
    __builtin_amdgcn_s_barrier(); }

    // prologue: stage halves 0..2 (12 loads); force 0,1 (keep 2's 4);
    // barrier; pre-issue half 0's reads into bank 0.
    STG13(0, 0); STG13(1, 1); STG13(2, 2);
    VMW(4);
    __builtin_amdgcn_s_barrier();
    RD13(0, 0);

#pragma unroll 1
    for (int h = 0; h < 28; h += 4) {           // halves 0..27
        HALF13(0, RD13(1, 1), STG13(3, h + 3), VMW(4));
        HALF13(1, RD13(2, 0), STG13(0, h + 4), VMW(4));
        HALF13(0 + 0, RD13(3, 1), STG13(1, h + 5), VMW(4));   // BC=0 (h+2)
        HALF13(1, RD13(0, 0), STG13(2, h + 6), VMW(4));       // BC=1 (h+3)
    }
    HALF13(0, RD13(1, 1), STG13(3, 31), VMW(4));   // half 28, force stage 30
    HALF13(1, RD13(2, 0), , VMW(0));               // half 29, force stage 31
    HALF13(0, RD13(3, 1), , );                     // half 30
    HALF13(1, , , );                               // half 31

    // Epilogue: silu(U)*V -> LDS bf16 [256][136] -> full-line stores
    __syncthreads();
    bf16_t* Ct = smem;
#pragma unroll
    for (int i = 0; i < 4; ++i)
#pragma unroll
        for (int j = 0; j < 4; ++j) {
            int r = wm * 64 + i * 16 + quad * 4;
            int c = wn * 64 + j * 16 + l16;
#pragma unroll
            for (int t = 0; t < 4; ++t) {
                float u = accU[i][j][t];
                float v = accV[i][j][t];
                float h = (u / (1.f + __expf(-u))) * v;
                Ct[(r + t) * 136 + c] = (bf16_t)h;
            }
        }
    __syncthreads();
#pragma unroll
    for (int s = 0; s < 8; ++s) {
        int r = s * 32 + (tid >> 4);
        int cb = (tid & 15) * 8;
        bf16x8 v = *(const bf16x8*)(Ct + r * 136 + cb);
        *(bf16x8*)(Hh + (size_t)(row0 + r) * N + col0 + cb) = v;
    }
#undef HALF13
#undef RD13
#undef STG13
}

// ---------- GEMM2: Out = Hh * W2 ----------
// Tile 256(M) x 256(N), 8 waves = 2M x 4N, per-wave 128x64.
// Slot bytes: A [0,16384) (row-half via +8192), B [16384,32768).
__global__ __launch_bounds__(512, 2) void gemm2k(const bf16_t* __restrict__ Hh,
                                                 const bf16_t* __restrict__ W2t,
                                                 float* __restrict__ Outc,
                                                 int row_base) {
    const int K = 2048, N = 1024;
    int nwg = gridDim.x, id = blockIdx.x;
    if ((nwg & 7) == 0) id = (id & 7) * (nwg >> 3) + (id >> 3);
    int nbx = nwg >> 2;
    int bx = id % nbx, by = id / nbx;
    int row0 = bx * 256, col0 = by * 256;
    int seg = ((row_base + row0) & 2047) >> 9;
    const bf16_t* Ag = Hh + (size_t)row0 * K;
    const bf16_t* Bg = W2t + ((size_t)seg * N + col0) * K;

    __shared__ __align__(16) bf16_t smem[65536];

    int tid = threadIdx.x, lane = tid & 63, w = tid >> 6;
    int wm = w >> 2, wn = w & 3;
    int quad = lane >> 4, l16 = lane & 15;

    int r0 = 2 * (tid >> 3) + ((tid >> 2) & 1);
    int c0 = (tid & 3) ^ ((tid >> 3) & 3);
    int offG  = r0 * K + c0 * 8;
    int offG2 = offG + 128 * K;

    int sigRd = ((l16 & 1) << 2) | (quad ^ ((l16 >> 1) & 3));
    int rdAB = ((wm * 64 + (l16 >> 1)) * 64 + sigRd * 8) * 2;   // + i*1024B; +4096B row-half
    int rdBB = ((wn * 32 + (l16 >> 1)) * 64 + sigRd * 8) * 2;   // + 16384B + j*1024B

    f32x4 acc[8][4];
    f32x4 z = {0.f, 0.f, 0.f, 0.f};
#pragma unroll
    for (int i = 0; i < 8; ++i)
#pragma unroll
        for (int j = 0; j < 4; ++j) acc[i][j] = z;

    f32x4 af[2][4], ag[2][4], bfr[2][4];     // two register banks

#define STG2(slot, hh) { bf16_t* d_ = smem + (slot) * 16384; const int kg_ = (hh) * 32; \
    gload16(Ag + kg_ + offG,  d_ + tid * 8); \
    gload16(Ag + kg_ + offG2, d_ + 4096 + tid * 8); \
    gload16(Bg + kg_ + offG,  d_ + 8192 + tid * 8); \
    gload16(Bg + kg_ + offG2, d_ + 12288 + tid * 8); }

#define RD2(slotN, BN) {                                                        \
    int aA_ = (slotN) * 32768 + rdAB;                                           \
    int aB_ = (slotN) * 32768 + rdBB;                                           \
    DSR(af[BN][0], aA_, "offset:0");      DSR(af[BN][1], aA_, "offset:1024");   \
    DSR(af[BN][2], aA_, "offset:2048");   DSR(af[BN][3], aA_, "offset:3072");   \
    DSR(ag[BN][0], aA_, "offset:4096");   DSR(ag[BN][1], aA_, "offset:5120");   \
    DSR(ag[BN][2], aA_, "offset:6144");   DSR(ag[BN][3], aA_, "offset:7168");   \
    DSR(bfr[BN][0], aB_, "offset:16384"); DSR(bfr[BN][1], aB_, "offset:17408"); \
    DSR(bfr[BN][2], aB_, "offset:18432"); DSR(bfr[BN][3], aB_, "offset:19456"); }

#define HALF2(BC, RD, STG, WAIT) {                                              \
    LGKMN(0);                                                                   \
    RD;                                                                         \
    STG;                                                                        \
    __builtin_amdgcn_sched_barrier(0);                                          \
    __builtin_amdgcn_s_setprio(1);                                              \
    _Pragma("unroll")                                                           \
    for (int i_ = 0; i_ < 4; ++i_)                                              \
        _Pragma("unroll")                                                       \
        for (int j_ = 0; j_ < 4; ++j_)                                          \
            acc[i_][j_] = MFMA16(BC8(af[BC][i_]), BC8(bfr[BC][j_]), acc[i_][j_]); \
    _Pragma("unroll")                                                           \
    for (int i_ = 0; i_ < 4; ++i_)                                              \
        _Pragma("unroll")                                                       \
        for (int j_ = 0; j_ < 4; ++j_)                                          \
            acc[4 + i_][j_] = MFMA16(BC8(ag[BC][i_]), BC8(bfr[BC][j_]), acc[4 + i_][j_]); \
    __builtin_amdgcn_s_setprio(0);                                              \
    WAIT;                                                                       \
    __builtin_amdgcn_s_barrier(); }

    STG2(0, 0); STG2(1, 1); STG2(2, 2);
    VMW(4);
    __builtin_amdgcn_s_barrier();
    RD2(0, 0);

#pragma unroll 1
    for (int h = 0; h < 60; h += 4) {           // halves 0..59
        HALF2(0, RD2(1, 1), STG2(3, h + 3), VMW(4));
        HALF2(1, RD2(2, 0), STG2(0, h + 4), VMW(4));
        HALF2(0, RD2(3, 1), STG2(1, h + 5), VMW(4));
        HALF2(1, RD2(0, 0), STG2(2, h + 6), VMW(4));
    }
    HALF2(0, RD2(1, 1), STG2(3, 63), VMW(4));   // half 60, force stage 62
    HALF2(1, RD2(2, 0), , VMW(0));              // half 61, force stage 63
    HALF2(0, RD2(3, 1), , );                    // half 62
    HALF2(1, , , );                             // half 63

    // Epilogue: 4 x 64-row passes through f32 LDS [64][260], 1KB/row stores
    __syncthreads();
    float* smemf = (float*)smem;
    for (int pass = 0; pass < 4; ++pass) {
        if (pass) __syncthreads();
        if (wm == (pass >> 1)) {
            int mq = pass & 1;
#pragma unroll
            for (int i = 0; i < 4; ++i)
#pragma unroll
                for (int j = 0; j < 4; ++j) {
                    int r = i * 16 + quad * 4;
                    int c = wn * 64 + j * 16 + l16;
#pragma unroll
                    for (int t = 0; t < 4; ++t)
                        smemf[(r + t) * 260 + c] = acc[mq * 4 + i][j][t];
                }
        }
        __syncthreads();
#pragma unroll
        for (int s = 0; s < 8; ++s) {
            int r = s * 8 + w;
            f32x4 v = *(const f32x4*)(smemf + r * 260 + lane * 4);
            *(f32x4*)(Outc + (size_t)(row0 + pass * 64 + r) * N + col0 + lane * 4) = v;
        }
    }
#undef HALF2
#undef RD2
#undef STG2
}

extern "C" void kernel_launch(void* const* d_in, const int* in_sizes, int n_in,
                              void* d_out, int out_size, void* d_ws, size_t ws_size,
                              hipStream_t stream) {
    const float* x  = (const float*)d_in[0];   // fp32 [8,2048,1024]
    const float* w1 = (const float*)d_in[1];   // fp32 [4,1024,2048]
    const float* w3 = (const float*)d_in[2];   // fp32 [4,1024,2048]
    const float* w2 = (const float*)d_in[3];   // fp32 [4,2048,1024]
    float* out = (float*)d_out;                // fp32 [8,2048,1024]

    const size_t WSEG = (size_t)4 * 1024 * 2048;
    bf16_t* w1t = (bf16_t*)d_ws;
    bf16_t* w3t = w1t + WSEG;
    bf16_t* w2t = w3t + WSEG;
    bf16_t* dyn = w2t + WSEG;

    transcvt64<<<dim3(32, 16, 4), 256, 0, stream>>>(w1, (unsigned short*)w1t, 1024, 2048);
    transcvt64<<<dim3(32, 16, 4), 256, 0, stream>>>(w3, (unsigned short*)w3t, 1024, 2048);
    transcvt64<<<dim3(16, 32, 4), 256, 0, stream>>>(w2, (unsigned short*)w2t, 2048, 1024);

    const int TOTAL_ROWS = 16384;
    size_t wbytes = 3 * WSEG * sizeof(bf16_t);
    size_t avail = (ws_size > wbytes) ? ws_size - wbytes : 0;
    int chunk_rows = TOTAL_ROWS;
    while (chunk_rows > 256 && (size_t)chunk_rows * 6144 > avail)
        chunk_rows >>= 1;

    for (int rb = 0; rb < TOTAL_ROWS; rb += chunk_rows) {
        bf16_t* Xb = dyn;
        bf16_t* Hh = dyn + (size_t)chunk_rows * 1024;
        cvtx<<<chunk_rows / 2, 256, 0, stream>>>(x + (size_t)rb * 1024, Xb);
        gemm13<<<(chunk_rows / 256) * 16, 512, 0, stream>>>(Xb, w1t, w3t, Hh, rb);
        gemm2k<<<(chunk_rows / 256) * 4, 512, 0, stream>>>(Hh, w2t, out + (size_t)rb * 1024, rb);
    }
}

// Round 6
// 402.991 us; speedup vs baseline: 1.4693x; 1.4693x over previous
//
#include <hip/hip_runtime.h>
#include <hip/hip_bf16.h>

typedef __bf16 bf16_t;
typedef __attribute__((ext_vector_type(8))) __bf16 bf16x8;
typedef __attribute__((ext_vector_type(4))) float f32x4;
typedef __attribute__((ext_vector_type(8))) unsigned short ushort8v;

#define MFMA16(a, b, c) __builtin_amdgcn_mfma_f32_16x16x32_bf16((a), (b), (c), 0, 0, 0)
#define BC8(x) __builtin_bit_cast(bf16x8, (x))

__device__ __forceinline__ unsigned short f2bf(float f) {
    bf16_t b = (bf16_t)f;
    return __builtin_bit_cast(unsigned short, b);
}

__device__ __forceinline__ void gload16(const void* g, void* l) {
    __builtin_amdgcn_global_load_lds(
        (const __attribute__((address_space(1))) void*)g,
        (__attribute__((address_space(3))) void*)l,
        16, 0, 0);
}

// ---------- fp32 -> bf16 elementwise convert (for X) ----------
__global__ __launch_bounds__(256) void cvtx(const float* __restrict__ src,
                                            bf16_t* __restrict__ dst) {
    size_t i = ((size_t)blockIdx.x * 256 + threadIdx.x) * 8;
    f32x4 v0 = *(const f32x4*)(src + i);
    f32x4 v1 = *(const f32x4*)(src + i + 4);
    bf16x8 o;
    o[0] = (bf16_t)v0[0]; o[1] = (bf16_t)v0[1];
    o[2] = (bf16_t)v0[2]; o[3] = (bf16_t)v0[3];
    o[4] = (bf16_t)v1[0]; o[5] = (bf16_t)v1[1];
    o[6] = (bf16_t)v1[2]; o[7] = (bf16_t)v1[3];
    *(bf16x8*)(dst + i) = o;
}

// ---------- batched 64x64 transpose + fp32->bf16 convert ----------
__global__ __launch_bounds__(256) void transcvt64(const float* __restrict__ src,
                                                  unsigned short* __restrict__ dst,
                                                  int R, int C) {
    __shared__ __align__(16) unsigned short tile[64][66];
    size_t off = (size_t)blockIdx.z * R * C;
    const float* s = src + off;
    unsigned short* d = dst + off;
    int tr = blockIdx.y * 64, tc = blockIdx.x * 64;
    int tid = threadIdx.x;
    int lr = tid >> 4;
    int lc = (tid & 15) * 4;
#pragma unroll
    for (int p = 0; p < 4; ++p) {
        int r = p * 16 + lr;
        f32x4 v = *(const f32x4*)(s + (size_t)(tr + r) * C + tc + lc);
        tile[r][lc + 0] = f2bf(v[0]); tile[r][lc + 1] = f2bf(v[1]);
        tile[r][lc + 2] = f2bf(v[2]); tile[r][lc + 3] = f2bf(v[3]);
    }
    __syncthreads();
#pragma unroll
    for (int q = 0; q < 2; ++q) {
        int item = q * 256 + tid;
        int oc = item >> 3;            // column 0..63
        int rb = (item & 7) * 8;       // row octet
        ushort8v v;
#pragma unroll
        for (int t = 0; t < 8; ++t) v[t] = tile[rb + t][oc];
        *(ushort8v*)(d + (size_t)(tc + oc) * R + tr + rb) = v;
    }
}

// =====================================================================
// Ring-buffered GEMMs, m201-style FINE PHASE SPLIT (T3+T4+T5 gate).
// LDS = 4 ring slots x 32KB (one K=32 half-tile). Each half = TWO phases,
// each {4-8 ds_read | 2 global_load_lds | [vmcnt] | s_barrier | lgkm0 |
// setprio1, 16 MFMA, setprio0 | s_barrier}. 16-MFMA clusters + per-phase
// barriers create the wave role-split that lets setprio arbitrate
// (m218b/m196); counted vmcnt(8) keeps 2 future halves in flight.
// Addressing/swizzle identical to the verified R2/R4 kernels.
// Safety ledger unchanged from R2/R4:
//   slot(h) staged-visible: VMW in half h-1 forces its loads; the
//     following barrier orders cross-wave before half h's reads.
//   STG(h+3) writes slot (h-1)&3: all waves' lgkm0 in half h-1 drained
//     their slot(h-1) reads; end-barrier precedes any STG at half h.
// =====================================================================

#define LGKMN(n) { asm volatile("s_waitcnt lgkmcnt(" #n ")" ::: "memory"); \
                   __builtin_amdgcn_sched_barrier(0); }
#define VMW(n) asm volatile("s_waitcnt vmcnt(" #n ")" ::: "memory")
#define DSR(dst, a, OFF) asm volatile("ds_read_b128 %0, %1 " OFF : "=v"(dst) : "v"(a))

// ---------- GEMM1 fused: Hh = silu(X*W1) * (X*W3) ----------
// Tile 256(M) x 128(N), 8 waves = 4M x 2N, per-wave 64x64 dual (U,V).
// Slot bytes: A rows0-127 [0,8192), A rows128-255 [8192,16384),
// B1 [16384,24576), B3 [24576,32768). Slot stride 32768 B.
__global__ __launch_bounds__(512, 2) void gemm13(const bf16_t* __restrict__ Xb,
                                                 const bf16_t* __restrict__ W1t,
                                                 const bf16_t* __restrict__ W3t,
                                                 bf16_t* __restrict__ Hh,
                                                 int row_base) {
    const int K = 1024, N = 2048;
    int nwg = gridDim.x, id = blockIdx.x;
    if ((nwg & 7) == 0) id = (id & 7) * (nwg >> 3) + (id >> 3);  // XCD swizzle
    int nbx = nwg >> 4;
    int bx = id % nbx, by = id / nbx;      // col-major: co-resident share W-panels
    int row0 = bx * 256, col0 = by * 128;
    int seg = ((row_base + row0) & 2047) >> 9;
    const bf16_t* Ag  = Xb + (size_t)row0 * K;
    const bf16_t* B1g = W1t + ((size_t)seg * N + col0) * K;
    const bf16_t* B3g = W3t + ((size_t)seg * N + col0) * K;

    __shared__ __align__(16) bf16_t smem[65536];     // 4 x 32KB slots

    int tid = threadIdx.x, lane = tid & 63, w = tid >> 6;
    int wm = w >> 1, wn = w & 1;
    int quad = lane >> 4, l16 = lane & 15;

    int r0 = 2 * (tid >> 3) + ((tid >> 2) & 1);
    int c0 = (tid & 3) ^ ((tid >> 3) & 3);
    int offG  = r0 * K + c0 * 8;
    int offG2 = offG + 128 * K;

    int sigRd = ((l16 & 1) << 2) | (quad ^ ((l16 >> 1) & 3));
    int rdAB = ((wm * 32 + (l16 >> 1)) * 64 + sigRd * 8) * 2;   // byte addr, A region
    int rdBB = ((wn * 32 + (l16 >> 1)) * 64 + sigRd * 8) * 2;   // byte addr, B region

    f32x4 accU[4][4], accV[4][4];
    f32x4 z = {0.f, 0.f, 0.f, 0.f};
#pragma unroll
    for (int i = 0; i < 4; ++i)
#pragma unroll
        for (int j = 0; j < 4; ++j) { accU[i][j] = z; accV[i][j] = z; }

    f32x4 af[4], bU[4], bV[4];

#define STGA13(slot, hh) { bf16_t* d_ = smem + (slot) * 16384; const int kg_ = (hh) * 32; \
    gload16(Ag + kg_ + offG,  d_ + tid * 8); \
    gload16(Ag + kg_ + offG2, d_ + 4096 + tid * 8); }
#define STGB13(slot, hh) { bf16_t* d_ = smem + (slot) * 16384; const int kg_ = (hh) * 32; \
    gload16(B1g + kg_ + offG, d_ + 8192 + tid * 8); \
    gload16(B3g + kg_ + offG, d_ + 12288 + tid * 8); }

// Phase A: read af(4) + bU(4); stage next A half; 16 U-MFMA.
#define PHA13(slot, STG) {                                                      \
    int aA_ = (slot) * 32768 + rdAB;                                            \
    int aB_ = (slot) * 32768 + rdBB;                                            \
    DSR(af[0], aA_, "offset:0");     DSR(af[1], aA_, "offset:1024");            \
    DSR(af[2], aA_, "offset:2048");  DSR(af[3], aA_, "offset:3072");            \
    DSR(bU[0], aB_, "offset:16384"); DSR(bU[1], aB_, "offset:17408");           \
    DSR(bU[2], aB_, "offset:18432"); DSR(bU[3], aB_, "offset:19456");           \
    STG;                                                                        \
    __builtin_amdgcn_s_barrier();                                               \
    LGKMN(0);                                                                   \
    __builtin_amdgcn_s_setprio(1);                                              \
    _Pragma("unroll")                                                           \
    for (int i_ = 0; i_ < 4; ++i_)                                              \
        _Pragma("unroll")                                                       \
        for (int j_ = 0; j_ < 4; ++j_)                                          \
            accU[i_][j_] = MFMA16(BC8(af[i_]), BC8(bU[j_]), accU[i_][j_]);      \
    __builtin_amdgcn_s_setprio(0);                                              \
    __builtin_amdgcn_s_barrier(); }

// Phase B: read bV(4); stage next B half; counted vmcnt; 16 V-MFMA (reuses af).
#define PHB13(slot, STG, WAIT) {                                                \
    int aB_ = (slot) * 32768 + rdBB;                                            \
    DSR(bV[0], aB_, "offset:24576"); DSR(bV[1], aB_, "offset:25600");           \
    DSR(bV[2], aB_, "offset:26624"); DSR(bV[3], aB_, "offset:27648");           \
    STG;                                                                        \
    WAIT;                                                                       \
    __builtin_amdgcn_s_barrier();                                               \
    LGKMN(0);                                                                   \
    __builtin_amdgcn_s_setprio(1);                                              \
    _Pragma("unroll")                                                           \
    for (int i_ = 0; i_ < 4; ++i_)                                              \
        _Pragma("unroll")                                                       \
        for (int j_ = 0; j_ < 4; ++j_)                                          \
            accV[i_][j_] = MFMA16(BC8(af[i_]), BC8(bV[j_]), accV[i_][j_]);      \
    __builtin_amdgcn_s_setprio(0);                                              \
    __builtin_amdgcn_s_barrier(); }

    // prologue: stage halves 0..2 (12 loads); force half 0 (keep 8); barrier
    STGA13(0, 0); STGB13(0, 0);
    STGA13(1, 1); STGB13(1, 1);
    STGA13(2, 2); STGB13(2, 2);
    VMW(8);
    __builtin_amdgcn_s_barrier();

#pragma unroll 1
    for (int h = 0; h < 28; h += 4) {           // halves 0..27, stage 3..33
        PHA13(0, STGA13(3, h + 3)); PHB13(0, STGB13(3, h + 3), VMW(8));
        PHA13(1, STGA13(0, h + 4)); PHB13(1, STGB13(0, h + 4), VMW(8));
        PHA13(2, STGA13(1, h + 5)); PHB13(2, STGB13(1, h + 5), VMW(8));
        PHA13(3, STGA13(2, h + 6)); PHB13(3, STGB13(2, h + 6), VMW(8));
    }
    PHA13(0, STGA13(3, 31)); PHB13(0, STGB13(3, 31), VMW(8));  // half 28
    PHA13(1, );              PHB13(1, , VMW(4));               // half 29
    PHA13(2, );              PHB13(2, , VMW(0));               // half 30
    PHA13(3, );              PHB13(3, , );                     // half 31

    // Epilogue: silu(U)*V -> LDS bf16 [256][136] -> full-line stores
    __syncthreads();
    bf16_t* Ct = smem;
#pragma unroll
    for (int i = 0; i < 4; ++i)
#pragma unroll
        for (int j = 0; j < 4; ++j) {
            int r = wm * 64 + i * 16 + quad * 4;
            int c = wn * 64 + j * 16 + l16;
#pragma unroll
            for (int t = 0; t < 4; ++t) {
                float u = accU[i][j][t];
                float v = accV[i][j][t];
                float h = (u / (1.f + __expf(-u))) * v;
                Ct[(r + t) * 136 + c] = (bf16_t)h;
            }
        }
    __syncthreads();
#pragma unroll
    for (int s = 0; s < 8; ++s) {
        int r = s * 32 + (tid >> 4);
        int cb = (tid & 15) * 8;
        bf16x8 v = *(const bf16x8*)(Ct + r * 136 + cb);
        *(bf16x8*)(Hh + (size_t)(row0 + r) * N + col0 + cb) = v;
    }
#undef PHA13
#undef PHB13
#undef STGA13
#undef STGB13
}

// ---------- GEMM2: Out = Hh * W2 ----------
// Tile 256(M) x 256(N), 8 waves = 2M x 4N, per-wave 128x64.
// Slot bytes: A [0,16384) (row-half via +8192... per R4: +4096B group), B [16384,32768).
__global__ __launch_bounds__(512, 2) void gemm2k(const bf16_t* __restrict__ Hh,
                                                 const bf16_t* __restrict__ W2t,
                                                 float* __restrict__ Outc,
                                                 int row_base) {
    const int K = 2048, N = 1024;
    int nwg = gridDim.x, id = blockIdx.x;
    if ((nwg & 7) == 0) id = (id & 7) * (nwg >> 3) + (id >> 3);
    int nbx = nwg >> 2;
    int bx = id % nbx, by = id / nbx;
    int row0 = bx * 256, col0 = by * 256;
    int seg = ((row_base + row0) & 2047) >> 9;
    const bf16_t* Ag = Hh + (size_t)row0 * K;
    const bf16_t* Bg = W2t + ((size_t)seg * N + col0) * K;

    __shared__ __align__(16) bf16_t smem[65536];

    int tid = threadIdx.x, lane = tid & 63, w = tid >> 6;
    int wm = w >> 2, wn = w & 3;
    int quad = lane >> 4, l16 = lane & 15;

    int r0 = 2 * (tid >> 3) + ((tid >> 2) & 1);
    int c0 = (tid & 3) ^ ((tid >> 3) & 3);
    int offG  = r0 * K + c0 * 8;
    int offG2 = offG + 128 * K;

    int sigRd = ((l16 & 1) << 2) | (quad ^ ((l16 >> 1) & 3));
    int rdAB = ((wm * 64 + (l16 >> 1)) * 64 + sigRd * 8) * 2;   // + i*1024B; +4096B row-half
    int rdBB = ((wn * 32 + (l16 >> 1)) * 64 + sigRd * 8) * 2;   // + 16384B + j*1024B

    f32x4 acc[8][4];
    f32x4 z = {0.f, 0.f, 0.f, 0.f};
#pragma unroll
    for (int i = 0; i < 8; ++i)
#pragma unroll
        for (int j = 0; j < 4; ++j) acc[i][j] = z;

    f32x4 af[4], ag[4], bfr[4];

#define STGA2(slot, hh) { bf16_t* d_ = smem + (slot) * 16384; const int kg_ = (hh) * 32; \
    gload16(Ag + kg_ + offG,  d_ + tid * 8); \
    gload16(Ag + kg_ + offG2, d_ + 4096 + tid * 8); }
#define STGB2(slot, hh) { bf16_t* d_ = smem + (slot) * 16384; const int kg_ = (hh) * 32; \
    gload16(Bg + kg_ + offG,  d_ + 8192 + tid * 8); \
    gload16(Bg + kg_ + offG2, d_ + 12288 + tid * 8); }

// Phase A: read af(4) + bfr(4); stage next A half; 16 MFMA (rows 0-63).
#define PHA2(slot, STG) {                                                       \
    int aA_ = (slot) * 32768 + rdAB;                                            \
    int aB_ = (slot) * 32768 + rdBB;                                            \
    DSR(af[0], aA_, "offset:0");      DSR(af[1], aA_, "offset:1024");           \
    DSR(af[2], aA_, "offset:2048");   DSR(af[3], aA_, "offset:3072");           \
    DSR(bfr[0], aB_, "offset:16384"); DSR(bfr[1], aB_, "offset:17408");         \
    DSR(bfr[2], aB_, "offset:18432"); DSR(bfr[3], aB_, "offset:19456");         \
    STG;                                                                        \
    __builtin_amdgcn_s_barrier();                                               \
    LGKMN(0);                                                                   \
    __builtin_amdgcn_s_setprio(1);                                              \
    _Pragma("unroll")                                                           \
    for (int i_ = 0; i_ < 4; ++i_)                                              \
        _Pragma("unroll")                                                       \
        for (int j_ = 0; j_ < 4; ++j_)                                          \
            acc[i_][j_] = MFMA16(BC8(af[i_]), BC8(bfr[j_]), acc[i_][j_]);       \
    __builtin_amdgcn_s_setprio(0);                                              \
    __builtin_amdgcn_s_barrier(); }

// Phase B: read ag(4); stage next B half; counted vmcnt; 16 MFMA (rows 64-127).
#define PHB2(slot, STG, WAIT) {                                                 \
    int aA_ = (slot) * 32768 + rdAB;                                            \
    DSR(ag[0], aA_, "offset:4096");   DSR(ag[1], aA_, "offset:5120");           \
    DSR(ag[2], aA_, "offset:6144");   DSR(ag[3], aA_, "offset:7168");           \
    STG;                                                                        \
    WAIT;                                                                       \
    __builtin_amdgcn_s_barrier();                                               \
    LGKMN(0);                                                                   \
    __builtin_amdgcn_s_setprio(1);                                              \
    _Pragma("unroll")                                                           \
    for (int i_ = 0; i_ < 4; ++i_)                                              \
        _Pragma("unroll")                                                       \
        for (int j_ = 0; j_ < 4; ++j_)                                          \
            acc[4 + i_][j_] = MFMA16(BC8(ag[i_]), BC8(bfr[j_]), acc[4 + i_][j_]); \
    __builtin_amdgcn_s_setprio(0);                                              \
    __builtin_amdgcn_s_barrier(); }

    STGA2(0, 0); STGB2(0, 0);
    STGA2(1, 1); STGB2(1, 1);
    STGA2(2, 2); STGB2(2, 2);
    VMW(8);
    __builtin_amdgcn_s_barrier();

#pragma unroll 1
    for (int h = 0; h < 60; h += 4) {           // halves 0..59, stage 3..65
        PHA2(0, STGA2(3, h + 3)); PHB2(0, STGB2(3, h + 3), VMW(8));
        PHA2(1, STGA2(0, h + 4)); PHB2(1, STGB2(0, h + 4), VMW(8));
        PHA2(2, STGA2(1, h + 5)); PHB2(2, STGB2(1, h + 5), VMW(8));
        PHA2(3, STGA2(2, h + 6)); PHB2(3, STGB2(2, h + 6), VMW(8));
    }
    PHA2(0, STGA2(3, 63)); PHB2(0, STGB2(3, 63), VMW(8));  // half 60
    PHA2(1, );             PHB2(1, , VMW(4));              // half 61
    PHA2(2, );             PHB2(2, , VMW(0));              // half 62
    PHA2(3, );             PHB2(3, , );                    // half 63

    // Epilogue: 4 x 64-row passes through f32 LDS [64][260], 1KB/row stores
    __syncthreads();
    float* smemf = (float*)smem;
    for (int pass = 0; pass < 4; ++pass) {
        if (pass) __syncthreads();
        if (wm == (pass >> 1)) {
            int mq = pass & 1;
#pragma unroll
            for (int i = 0; i < 4; ++i)
#pragma unroll
                for (int j = 0; j < 4; ++j) {
                    int r = i * 16 + quad * 4;
                    int c = wn * 64 + j * 16 + l16;
#pragma unroll
                    for (int t = 0; t < 4; ++t)
                        smemf[(r + t) * 260 + c] = acc[mq * 4 + i][j][t];
                }
        }
        __syncthreads();
#pragma unroll
        for (int s = 0; s < 8; ++s) {
            int r = s * 8 + w;
            f32x4 v = *(const f32x4*)(smemf + r * 260 + lane * 4);
            *(f32x4*)(Outc + (size_t)(row0 + pass * 64 + r) * N + col0 + lane * 4) = v;
        }
    }
#undef PHA2
#undef PHB2
#undef STGA2
#undef STGB2
}

extern "C" void kernel_launch(void* const* d_in, const int* in_sizes, int n_in,
                              void* d_out, int out_size, void* d_ws, size_t ws_size,
                              hipStream_t stream) {
    const float* x  = (const float*)d_in[0];   // fp32 [8,2048,1024]
    const float* w1 = (const float*)d_in[1];   // fp32 [4,1024,2048]
    const float* w3 = (const float*)d_in[2];   // fp32 [4,1024,2048]
    const float* w2 = (const float*)d_in[3];   // fp32 [4,2048,1024]
    float* out = (float*)d_out;                // fp32 [8,2048,1024]

    const size_t WSEG = (size_t)4 * 1024 * 2048;
    bf16_t* w1t = (bf16_t*)d_ws;
    bf16_t* w3t = w1t + WSEG;
    bf16_t* w2t = w3t + WSEG;
    bf16_t* dyn = w2t + WSEG;

    transcvt64<<<dim3(32, 16, 4), 256, 0, stream>>>(w1, (unsigned short*)w1t, 1024, 2048);
    transcvt64<<<dim3(32, 16, 4), 256, 0, stream>>>(w3, (unsigned short*)w3t, 1024, 2048);
    transcvt64<<<dim3(16, 32, 4), 256, 0, stream>>>(w2, (unsigned short*)w2t, 2048, 1024);

    const int TOTAL_ROWS = 16384;
    size_t wbytes = 3 * WSEG * sizeof(bf16_t);
    size_t avail = (ws_size > wbytes) ? ws_size - wbytes : 0;
    int chunk_rows = TOTAL_ROWS;
    while (chunk_rows > 256 && (size_t)chunk_rows * 6144 > avail)
        chunk_rows >>= 1;

    for (int rb = 0; rb < TOTAL_ROWS; rb += chunk_rows) {
        bf16_t* Xb = dyn;
        bf16_t* Hh = dyn + (size_t)chunk_rows * 1024;
        cvtx<<<chunk_rows / 2, 256, 0, stream>>>(x + (size_t)rb * 1024, Xb);
        gemm13<<<(chunk_rows / 256) * 16, 512, 0, stream>>>(Xb, w1t, w3t, Hh, rb);
        gemm2k<<<(chunk_rows / 256) * 4, 512, 0, stream>>>(Hh, w2t, out + (size_t)rb * 1024, rb);
    }
}

// Round 7
// 401.521 us; speedup vs baseline: 1.4747x; 1.0037x over previous
//
#include <hip/hip_runtime.h>
#include <hip/hip_bf16.h>

typedef __bf16 bf16_t;
typedef __attribute__((ext_vector_type(8))) __bf16 bf16x8;
typedef __attribute__((ext_vector_type(4))) float f32x4;
typedef __attribute__((ext_vector_type(8))) unsigned short ushort8v;

#define MFMA16(a, b, c) __builtin_amdgcn_mfma_f32_16x16x32_bf16((a), (b), (c), 0, 0, 0)
#define BC8(x) __builtin_bit_cast(bf16x8, (x))

__device__ __forceinline__ unsigned short f2bf(float f) {
    bf16_t b = (bf16_t)f;
    return __builtin_bit_cast(unsigned short, b);
}

__device__ __forceinline__ void gload16(const void* g, void* l) {
    __builtin_amdgcn_global_load_lds(
        (const __attribute__((address_space(1))) void*)g,
        (__attribute__((address_space(3))) void*)l,
        16, 0, 0);
}

// ---------- fp32 -> bf16 elementwise convert (for X) ----------
__global__ __launch_bounds__(256) void cvtx(const float* __restrict__ src,
                                            bf16_t* __restrict__ dst) {
    size_t i = ((size_t)blockIdx.x * 256 + threadIdx.x) * 8;
    f32x4 v0 = *(const f32x4*)(src + i);
    f32x4 v1 = *(const f32x4*)(src + i + 4);
    bf16x8 o;
    o[0] = (bf16_t)v0[0]; o[1] = (bf16_t)v0[1];
    o[2] = (bf16_t)v0[2]; o[3] = (bf16_t)v0[3];
    o[4] = (bf16_t)v1[0]; o[5] = (bf16_t)v1[1];
    o[6] = (bf16_t)v1[2]; o[7] = (bf16_t)v1[3];
    *(bf16x8*)(dst + i) = o;
}

// ---------- batched 64x64 transpose + fp32->bf16 convert ----------
__global__ __launch_bounds__(256) void transcvt64(const float* __restrict__ src,
                                                  unsigned short* __restrict__ dst,
                                                  int R, int C) {
    __shared__ __align__(16) unsigned short tile[64][66];
    size_t off = (size_t)blockIdx.z * R * C;
    const float* s = src + off;
    unsigned short* d = dst + off;
    int tr = blockIdx.y * 64, tc = blockIdx.x * 64;
    int tid = threadIdx.x;
    int lr = tid >> 4;
    int lc = (tid & 15) * 4;
#pragma unroll
    for (int p = 0; p < 4; ++p) {
        int r = p * 16 + lr;
        f32x4 v = *(const f32x4*)(s + (size_t)(tr + r) * C + tc + lc);
        tile[r][lc + 0] = f2bf(v[0]); tile[r][lc + 1] = f2bf(v[1]);
        tile[r][lc + 2] = f2bf(v[2]); tile[r][lc + 3] = f2bf(v[3]);
    }
    __syncthreads();
#pragma unroll
    for (int q = 0; q < 2; ++q) {
        int item = q * 256 + tid;
        int oc = item >> 3;            // column 0..63
        int rb = (item & 7) * 8;       // row octet
        ushort8v v;
#pragma unroll
        for (int t = 0; t < 8; ++t) v[t] = tile[rb + t][oc];
        *(ushort8v*)(d + (size_t)(tc + oc) * R + tr + rb) = v;
    }
}

// =====================================================================
// 2-blocks/CU GEMMs: 128-wide tiles, 256 threads (4 waves), ring-3 LDS
// (3 x 24KB slots = 72KB -> exactly 2 blocks/CU at 160KB). Cross-BLOCK
// overlap replaces the intra-block stagger that barriers kill: when one
// block waits on lgkmcnt/barrier, the co-resident block's waves feed the
// MFMA pipe (m114 mechanism). Half body = R4's verified best: 12 asm
// ds_read_b128, counted lgkm(4)->16 MFMA->lgkm(0)->16 MFMA, one counted
// vmcnt, ONE barrier per half.
// Ring-3 ledger (6 gloads/half/thread): invariant at each half boundary =
// 6 outstanding (next half's). Half h: reads slot h%3; stages h+2 into
// slot (h+2)%3 = (h-1)%3 (its readers drained by lgkm0 in half h-1 +
// end-barrier); VMW(6) forces h+1's loads. Tails drain 6 -> 0.
// Staging swizzle per 8KB region (128 rows x 32k) unchanged; 256-thread
// staging = 2 passes (pass p -> rows +64p, same chunk perm: derivation
// r0(p*256+tid) = p*64 + r0(tid), c0 unchanged since 32 = 0 mod 4).
// =====================================================================

#define LGKMN(n) { asm volatile("s_waitcnt lgkmcnt(" #n ")" ::: "memory"); \
                   __builtin_amdgcn_sched_barrier(0); }
#define VMW(n) asm volatile("s_waitcnt vmcnt(" #n ")" ::: "memory")
#define DSR(dst, a, OFF) asm volatile("ds_read_b128 %0, %1 " OFF : "=v"(dst) : "v"(a))

// ---------- GEMM1 fused: Hh = silu(X*W1) * (X*W3) ----------
// Tile 128(M) x 128(N), 4 waves = 2M x 2N, per-wave 64x64 dual (U,V).
// Slot bytes: A [0,8192), B1 [8192,16384), B3 [16384,24576). 3 slots.
__global__ __launch_bounds__(256, 2) void gemm13(const bf16_t* __restrict__ Xb,
                                                 const bf16_t* __restrict__ W1t,
                                                 const bf16_t* __restrict__ W3t,
                                                 bf16_t* __restrict__ Hh,
                                                 int row_base) {
    const int K = 1024, N = 2048;
    int nwg = gridDim.x, id = blockIdx.x;
    if ((nwg & 7) == 0) id = (id & 7) * (nwg >> 3) + (id >> 3);  // XCD swizzle
    int nbx = nwg >> 4;                    // row blocks (16 col blocks)
    int bx = id % nbx, by = id / nbx;      // col-major: co-resident share W-panels
    int row0 = bx * 128, col0 = by * 128;
    int seg = ((row_base + row0) & 2047) >> 9;
    const bf16_t* Ag  = Xb + (size_t)row0 * K;
    const bf16_t* B1g = W1t + ((size_t)seg * N + col0) * K;
    const bf16_t* B3g = W3t + ((size_t)seg * N + col0) * K;

    __shared__ __align__(16) bf16_t smem[36864];     // 3 x 24KB slots

    int tid = threadIdx.x, lane = tid & 63, w = tid >> 6;
    int wm = w >> 1, wn = w & 1;
    int quad = lane >> 4, l16 = lane & 15;

    int r0 = 2 * (tid >> 3) + ((tid >> 2) & 1);
    int c0 = (tid & 3) ^ ((tid >> 3) & 3);
    int offG = r0 * K + c0 * 8;            // pass stride: +64 rows = +65536 elems

    int sigRd = ((l16 & 1) << 2) | (quad ^ ((l16 >> 1) & 3));
    int rdAB = ((wm * 32 + (l16 >> 1)) * 64 + sigRd * 8) * 2;   // byte, A region
    int rdBB = ((wn * 32 + (l16 >> 1)) * 64 + sigRd * 8) * 2;   // byte, B region

    f32x4 accU[4][4], accV[4][4];
    f32x4 z = {0.f, 0.f, 0.f, 0.f};
#pragma unroll
    for (int i = 0; i < 4; ++i)
#pragma unroll
        for (int j = 0; j < 4; ++j) { accU[i][j] = z; accV[i][j] = z; }

    f32x4 af[4], bU[4], bV[4];

#define STG13(slot, hh) { bf16_t* d_ = smem + (slot) * 12288; const int kg_ = (hh) * 32; \
    gload16(Ag + kg_ + offG,          d_ + tid * 8); \
    gload16(Ag + kg_ + offG + 65536,  d_ + 2048 + tid * 8); \
    gload16(B1g + kg_ + offG,         d_ + 4096 + tid * 8); \
    gload16(B1g + kg_ + offG + 65536, d_ + 6144 + tid * 8); \
    gload16(B3g + kg_ + offG,         d_ + 8192 + tid * 8); \
    gload16(B3g + kg_ + offG + 65536, d_ + 10240 + tid * 8); }

#define HALF13(slot, STG, WAIT) {                                               \
    int aA_ = (slot) * 24576 + rdAB;                                            \
    int aB_ = (slot) * 24576 + 8192 + rdBB;                                     \
    DSR(af[0], aA_, "offset:0");    DSR(af[1], aA_, "offset:1024");             \
    DSR(af[2], aA_, "offset:2048"); DSR(af[3], aA_, "offset:3072");             \
    DSR(bU[0], aB_, "offset:0");    DSR(bU[1], aB_, "offset:1024");             \
    DSR(bU[2], aB_, "offset:2048"); DSR(bU[3], aB_, "offset:3072");             \
    DSR(bV[0], aB_, "offset:8192"); DSR(bV[1], aB_, "offset:9216");             \
    DSR(bV[2], aB_, "offset:10240");DSR(bV[3], aB_, "offset:11264");            \
    STG;                                                                        \
    LGKMN(4);                                                                   \
    __builtin_amdgcn_s_setprio(1);                                              \
    _Pragma("unroll")                                                           \
    for (int i_ = 0; i_ < 4; ++i_)                                              \
        _Pragma("unroll")                                                       \
        for (int j_ = 0; j_ < 4; ++j_)                                          \
            accU[i_][j_] = MFMA16(BC8(af[i_]), BC8(bU[j_]), accU[i_][j_]);      \
    __builtin_amdgcn_s_setprio(0);                                              \
    LGKMN(0);                                                                   \
    __builtin_amdgcn_s_setprio(1);                                              \
    _Pragma("unroll")                                                           \
    for (int i_ = 0; i_ < 4; ++i_)                                              \
        _Pragma("unroll")                                                       \
        for (int j_ = 0; j_ < 4; ++j_)                                          \
            accV[i_][j_] = MFMA16(BC8(af[i_]), BC8(bV[j_]), accV[i_][j_]);      \
    __builtin_amdgcn_s_setprio(0);                                              \
    WAIT;                                                                       \
    __builtin_amdgcn_s_barrier(); }

    // prologue: stage halves 0,1 (12 loads); force half 0 (keep 6); barrier
    STG13(0, 0); STG13(1, 1);
    VMW(6);
    __builtin_amdgcn_s_barrier();

#pragma unroll 1
    for (int h = 0; h < 27; h += 3) {           // halves 0..26, stage 2..28
        HALF13(0, STG13(2, h + 2), VMW(6));
        HALF13(1, STG13(0, h + 3), VMW(6));
        HALF13(2, STG13(1, h + 4), VMW(6));
    }
    HALF13(0, STG13(2, 29), VMW(6));            // half 27
    HALF13(1, STG13(0, 30), VMW(6));            // half 28
    HALF13(2, STG13(1, 31), VMW(6));            // half 29
    HALF13(0, , VMW(0));                        // half 30 -> forces 31
    HALF13(1, , );                              // half 31

    // Epilogue: silu(U)*V -> LDS bf16 [128][136] -> full-line stores
    __syncthreads();
    bf16_t* Ct = smem;
#pragma unroll
    for (int i = 0; i < 4; ++i)
#pragma unroll
        for (int j = 0; j < 4; ++j) {
            int r = wm * 64 + i * 16 + quad * 4;
            int c = wn * 64 + j * 16 + l16;
#pragma unroll
            for (int t = 0; t < 4; ++t) {
                float u = accU[i][j][t];
                float v = accV[i][j][t];
                float h = (u / (1.f + __expf(-u))) * v;
                Ct[(r + t) * 136 + c] = (bf16_t)h;
            }
        }
    __syncthreads();
#pragma unroll
    for (int s = 0; s < 8; ++s) {
        int r = s * 16 + (tid >> 4);
        int cb = (tid & 15) * 8;
        bf16x8 v = *(const bf16x8*)(Ct + r * 136 + cb);
        *(bf16x8*)(Hh + (size_t)(row0 + r) * N + col0 + cb) = v;
    }
#undef HALF13
#undef STG13
}

// ---------- GEMM2: Out = Hh * W2 ----------
// Tile 128(M) x 256(N), 4 waves = 2M x 2N, per-wave 64x128.
// Slot bytes: A [0,8192), B [8192,24576). 3 slots x 24KB.
__global__ __launch_bounds__(256, 2) void gemm2k(const bf16_t* __restrict__ Hh,
                                                 const bf16_t* __restrict__ W2t,
                                                 float* __restrict__ Outc,
                                                 int row_base) {
    const int K = 2048, N = 1024;
    int nwg = gridDim.x, id = blockIdx.x;
    if ((nwg & 7) == 0) id = (id & 7) * (nwg >> 3) + (id >> 3);
    int nbx = nwg >> 2;                    // row blocks (4 col blocks)
    int bx = id % nbx, by = id / nbx;
    int row0 = bx * 128, col0 = by * 256;
    int seg = ((row_base + row0) & 2047) >> 9;
    const bf16_t* Ag = Hh + (size_t)row0 * K;
    const bf16_t* Bg = W2t + ((size_t)seg * N + col0) * K;

    __shared__ __align__(16) bf16_t smem[36864];     // 3 x 24KB slots

    int tid = threadIdx.x, lane = tid & 63, w = tid >> 6;
    int wm = w >> 1, wn = w & 1;
    int quad = lane >> 4, l16 = lane & 15;

    int r0 = 2 * (tid >> 3) + ((tid >> 2) & 1);
    int c0 = (tid & 3) ^ ((tid >> 3) & 3);
    int offG = r0 * K + c0 * 8;            // pass stride: +64 rows = +131072 elems

    int sigRd = ((l16 & 1) << 2) | (quad ^ ((l16 >> 1) & 3));
    int rdAB = ((wm * 32 + (l16 >> 1)) * 64 + sigRd * 8) * 2;   // byte, A region
    int rdBB = ((wn * 64 + (l16 >> 1)) * 64 + sigRd * 8) * 2;   // byte, B region

    f32x4 acc[4][8];
    f32x4 z = {0.f, 0.f, 0.f, 0.f};
#pragma unroll
    for (int i = 0; i < 4; ++i)
#pragma unroll
        for (int j = 0; j < 8; ++j) acc[i][j] = z;

    f32x4 af[4], bfr[8];

#define STG2(slot, hh) { bf16_t* d_ = smem + (slot) * 12288; const int kg_ = (hh) * 32; \
    gload16(Ag + kg_ + offG,           d_ + tid * 8); \
    gload16(Ag + kg_ + offG + 131072,  d_ + 2048 + tid * 8); \
    gload16(Bg + kg_ + offG,           d_ + 4096 + tid * 8); \
    gload16(Bg + kg_ + offG + 131072,  d_ + 6144 + tid * 8); \
    gload16(Bg + kg_ + offG + 262144,  d_ + 8192 + tid * 8); \
    gload16(Bg + kg_ + offG + 393216,  d_ + 10240 + tid * 8); }

#define HALF2(slot, STG, WAIT) {                                                \
    int aA_ = (slot) * 24576 + rdAB;                                            \
    int aB_ = (slot) * 24576 + 8192 + rdBB;                                     \
    DSR(af[0], aA_, "offset:0");     DSR(af[1], aA_, "offset:1024");            \
    DSR(af[2], aA_, "offset:2048");  DSR(af[3], aA_, "offset:3072");            \
    DSR(bfr[0], aB_, "offset:0");    DSR(bfr[1], aB_, "offset:1024");           \
    DSR(bfr[2], aB_, "offset:2048"); DSR(bfr[3], aB_, "offset:3072");           \
    DSR(bfr[4], aB_, "offset:4096"); DSR(bfr[5], aB_, "offset:5120");           \
    DSR(bfr[6], aB_, "offset:6144"); DSR(bfr[7], aB_, "offset:7168");           \
    STG;                                                                        \
    LGKMN(4);                                                                   \
    __builtin_amdgcn_s_setprio(1);                                              \
    _Pragma("unroll")                                                           \
    for (int i_ = 0; i_ < 4; ++i_)                                              \
        _Pragma("unroll")                                                       \
        for (int j_ = 0; j_ < 4; ++j_)                                          \
            acc[i_][j_] = MFMA16(BC8(af[i_]), BC8(bfr[j_]), acc[i_][j_]);       \
    __builtin_amdgcn_s_setprio(0);                                              \
    LGKMN(0);                                                                   \
    __builtin_amdgcn_s_setprio(1);                                              \
    _Pragma("unroll")                                                           \
    for (int i_ = 0; i_ < 4; ++i_)                                              \
        _Pragma("unroll")                                                       \
        for (int j_ = 0; j_ < 4; ++j_)                                          \
            acc[i_][4 + j_] = MFMA16(BC8(af[i_]), BC8(bfr[4 + j_]), acc[i_][4 + j_]); \
    __builtin_amdgcn_s_setprio(0);                                              \
    WAIT;                                                                       \
    __builtin_amdgcn_s_barrier(); }

    STG2(0, 0); STG2(1, 1);
    VMW(6);
    __builtin_amdgcn_s_barrier();

#pragma unroll 1
    for (int h = 0; h < 60; h += 3) {           // halves 0..59, stage 2..61
        HALF2(0, STG2(2, h + 2), VMW(6));
        HALF2(1, STG2(0, h + 3), VMW(6));
        HALF2(2, STG2(1, h + 4), VMW(6));
    }
    HALF2(0, STG2(2, 62), VMW(6));              // half 60
    HALF2(1, STG2(0, 63), VMW(6));              // half 61
    HALF2(2, , VMW(0));                         // half 62 -> forces 63
    HALF2(0, , );                               // half 63 (slot 63%3 = 0)

    // Epilogue: 2 x 64-row passes through f32 LDS [64][260], 1KB/row stores
    __syncthreads();
    float* smemf = (float*)smem;
    for (int pass = 0; pass < 2; ++pass) {
        if (pass) __syncthreads();
        if (wm == pass) {
#pragma unroll
            for (int i = 0; i < 4; ++i)
#pragma unroll
                for (int j = 0; j < 8; ++j) {
                    int r = i * 16 + quad * 4;
                    int c = wn * 128 + j * 16 + l16;
#pragma unroll
                    for (int t = 0; t < 4; ++t)
                        smemf[(r + t) * 260 + c] = acc[i][j][t];
                }
        }
        __syncthreads();
#pragma unroll
        for (int s = 0; s < 16; ++s) {
            int r = s * 4 + (tid >> 6);
            int cb = (tid & 63) * 4;
            f32x4 v = *(const f32x4*)(smemf + r * 260 + cb);
            *(f32x4*)(Outc + (size_t)(row0 + pass * 64 + r) * N + col0 + cb) = v;
        }
    }
#undef HALF2
#undef STG2
}

extern "C" void kernel_launch(void* const* d_in, const int* in_sizes, int n_in,
                              void* d_out, int out_size, void* d_ws, size_t ws_size,
                              hipStream_t stream) {
    const float* x  = (const float*)d_in[0];   // fp32 [8,2048,1024]
    const float* w1 = (const float*)d_in[1];   // fp32 [4,1024,2048]
    const float* w3 = (const float*)d_in[2];   // fp32 [4,1024,2048]
    const float* w2 = (const float*)d_in[3];   // fp32 [4,2048,1024]
    float* out = (float*)d_out;                // fp32 [8,2048,1024]

    const size_t WSEG = (size_t)4 * 1024 * 2048;
    bf16_t* w1t = (bf16_t*)d_ws;
    bf16_t* w3t = w1t + WSEG;
    bf16_t* w2t = w3t + WSEG;
    bf16_t* dyn = w2t + WSEG;

    transcvt64<<<dim3(32, 16, 4), 256, 0, stream>>>(w1, (unsigned short*)w1t, 1024, 2048);
    transcvt64<<<dim3(32, 16, 4), 256, 0, stream>>>(w3, (unsigned short*)w3t, 1024, 2048);
    transcvt64<<<dim3(16, 32, 4), 256, 0, stream>>>(w2, (unsigned short*)w2t, 2048, 1024);

    const int TOTAL_ROWS = 16384;
    size_t wbytes = 3 * WSEG * sizeof(bf16_t);
    size_t avail = (ws_size > wbytes) ? ws_size - wbytes : 0;
    int chunk_rows = TOTAL_ROWS;
    while (chunk_rows > 128 && (size_t)chunk_rows * 6144 > avail)
        chunk_rows >>= 1;

    for (int rb = 0; rb < TOTAL_ROWS; rb += chunk_rows) {
        bf16_t* Xb = dyn;
        bf16_t* Hh = dyn + (size_t)chunk_rows * 1024;
        cvtx<<<chunk_rows / 2, 256, 0, stream>>>(x + (size_t)rb * 1024, Xb);
        gemm13<<<(chunk_rows / 128) * 16, 256, 0, stream>>>(Xb, w1t, w3t, Hh, rb);
        gemm2k<<<(chunk_rows / 128) * 4, 256, 0, stream>>>(Hh, w2t, out + (size_t)rb * 1024, rb);
    }
}